// Round 5
// baseline (69846.008 us; speedup 1.0000x reference)
//
#include <hip/hip_runtime.h>
#include <hip/hip_bf16.h>
#include <math.h>
#include <stdint.h>

#define B 8
#define T 1024
#define D 1024
#define H 16
#define DH 64
#define NSTEPS 4

#define NCHAIN 2            // batch split into 2 independent chains of 4 rows
#define NBLK_CHAIN 128      // blocks per chain
#define DIMS_PER_BLK 8      // 128 * 8 = 1024 dims

#define STG_PITCH 1032      // staging row pitch (words)

__device__ __forceinline__ float sigmoidf_(float x) { return 1.0f / (1.0f + expf(-x)); }

// ---------------------------------------------------------------------------
// Generic tiled fp32 GEMM: C[M,N] = A[M,K] @ W[N,K]^T + bias[N]
// MODE 0: C[m*N + n];  MODE 1: qkv scatter to q/k/v [B*H, T, DH]
// ---------------------------------------------------------------------------
template <int MODE>
__global__ __launch_bounds__(256) void gemm_kernel(
    const float* __restrict__ A, const float* __restrict__ W,
    const float* __restrict__ bias, float* __restrict__ C,
    int M, int N, int K, int ldw, int koff,
    float* __restrict__ qb, float* __restrict__ kb, float* __restrict__ vb)
{
    __shared__ float As[32][68];
    __shared__ float Ws[32][68];
    const int m0 = blockIdx.x * 64, n0 = blockIdx.y * 64;
    const int tid = threadIdx.x;
    const int tn = tid & 15, tm = tid >> 4;
    float acc[4][4] = {};

    for (int k0 = 0; k0 < K; k0 += 32) {
#pragma unroll
        for (int j = 0; j < 2; ++j) {
            int lin = tid + j * 256;
            int r = lin >> 3, c4 = lin & 7;
            float4 av = *(const float4*)(A + (size_t)(m0 + r) * K + k0 + c4 * 4);
            As[c4 * 4 + 0][r] = av.x; As[c4 * 4 + 1][r] = av.y;
            As[c4 * 4 + 2][r] = av.z; As[c4 * 4 + 3][r] = av.w;
            float4 wv = *(const float4*)(W + (size_t)(n0 + r) * ldw + koff + k0 + c4 * 4);
            Ws[c4 * 4 + 0][r] = wv.x; Ws[c4 * 4 + 1][r] = wv.y;
            Ws[c4 * 4 + 2][r] = wv.z; Ws[c4 * 4 + 3][r] = wv.w;
        }
        __syncthreads();
#pragma unroll
        for (int k = 0; k < 32; ++k) {
            float a_[4], b_[4];
            *(float4*)a_ = *(const float4*)&As[k][tm * 4];
            *(float4*)b_ = *(const float4*)&Ws[k][tn * 4];
#pragma unroll
            for (int i = 0; i < 4; ++i)
#pragma unroll
                for (int j = 0; j < 4; ++j) acc[i][j] += a_[i] * b_[j];
        }
        __syncthreads();
    }

#pragma unroll
    for (int i = 0; i < 4; ++i) {
        int m = m0 + tm * 4 + i;
#pragma unroll
        for (int j = 0; j < 4; ++j) {
            int n = n0 + tn * 4 + j;
            float v = acc[i][j] + bias[n];
            if (MODE == 0) {
                C[(size_t)m * N + n] = v;
            } else {
                int which = n >> 10;
                int hh = (n & 1023) >> 6;
                int dh = n & 63;
                int b = m >> 10, t = m & 1023;
                float* dst = (which == 0) ? qb : ((which == 1) ? kb : vb);
                dst[(((size_t)(b * H + hh)) * T + t) * DH + dh] = v;
            }
        }
    }
}

// ---------------------------------------------------------------------------
// Flash attention fp32 (unchanged)
// ---------------------------------------------------------------------------
__global__ __launch_bounds__(256) void attn_kernel(
    const float* __restrict__ qb, const float* __restrict__ kb,
    const float* __restrict__ vb, float* __restrict__ ctx)
{
    __shared__ float Qs[64][65];
    __shared__ float Ks[64][65];
    __shared__ float Vs[64][65];
    __shared__ float mrow[64], lrow[64], srow[64];
    __shared__ float tred[64][4];

    const int tid = threadIdx.x;
    const int row = tid & 63, seg = tid >> 6;
    const int bx = blockIdx.x;
    const int qblk = bx & 15;
    const int bh = bx >> 4;
    const float* qp = qb + (size_t)bh * T * DH;
    const float* kp = kb + (size_t)bh * T * DH;
    const float* vp = vb + (size_t)bh * T * DH;

#pragma unroll
    for (int i = 0; i < 4; ++i) {
        int lin = tid + i * 256;
        int r = lin >> 4, c4 = lin & 15;
        float4 v = *(const float4*)(qp + (size_t)(qblk * 64 + r) * DH + c4 * 4);
        Qs[r][c4 * 4 + 0] = v.x; Qs[r][c4 * 4 + 1] = v.y;
        Qs[r][c4 * 4 + 2] = v.z; Qs[r][c4 * 4 + 3] = v.w;
    }
    if (tid < 64) { mrow[tid] = -3.0e38f; lrow[tid] = 0.0f; }

    float Oacc[16];
#pragma unroll
    for (int j = 0; j < 16; ++j) Oacc[j] = 0.0f;

    for (int kt = 0; kt < 16; ++kt) {
        __syncthreads();
#pragma unroll
        for (int i = 0; i < 4; ++i) {
            int lin = tid + i * 256;
            int r = lin >> 4, c4 = lin & 15;
            float4 kv = *(const float4*)(kp + (size_t)(kt * 64 + r) * DH + c4 * 4);
            Ks[r][c4 * 4 + 0] = kv.x; Ks[r][c4 * 4 + 1] = kv.y;
            Ks[r][c4 * 4 + 2] = kv.z; Ks[r][c4 * 4 + 3] = kv.w;
            float4 vv = *(const float4*)(vp + (size_t)(kt * 64 + r) * DH + c4 * 4);
            Vs[r][c4 * 4 + 0] = vv.x; Vs[r][c4 * 4 + 1] = vv.y;
            Vs[r][c4 * 4 + 2] = vv.z; Vs[r][c4 * 4 + 3] = vv.w;
        }
        __syncthreads();

        float sacc[16];
#pragma unroll
        for (int j = 0; j < 16; ++j) sacc[j] = 0.0f;
        for (int k = 0; k < 64; ++k) {
            float qv = Qs[row][k];
#pragma unroll
            for (int j = 0; j < 16; ++j) sacc[j] += qv * Ks[seg * 16 + j][k];
        }
        float tmax = -3.0e38f;
#pragma unroll
        for (int j = 0; j < 16; ++j) { sacc[j] *= 0.125f; tmax = fmaxf(tmax, sacc[j]); }
        tred[row][seg] = tmax;
        __syncthreads();
        if (seg == 0) {
            float mt = fmaxf(fmaxf(tred[row][0], tred[row][1]),
                             fmaxf(tred[row][2], tred[row][3]));
            float mo = mrow[row];
            float mn = fmaxf(mo, mt);
            srow[row] = expf(mo - mn);
            mrow[row] = mn;
        }
        __syncthreads();
        float mn = mrow[row], sc = srow[row];
        float psum = 0.0f;
#pragma unroll
        for (int j = 0; j < 16; ++j) {
            float p = expf(sacc[j] - mn);
            Ks[row][seg * 16 + j] = p;
            psum += p;
        }
        tred[row][seg] = psum;
#pragma unroll
        for (int j = 0; j < 16; ++j) Oacc[j] *= sc;
        __syncthreads();
        if (seg == 0)
            lrow[row] = lrow[row] * sc +
                        (tred[row][0] + tred[row][1] + tred[row][2] + tred[row][3]);
        for (int kj = 0; kj < 64; ++kj) {
            float pv = Ks[row][kj];
#pragma unroll
            for (int j = 0; j < 16; ++j) Oacc[j] += pv * Vs[kj][seg * 16 + j];
        }
    }
    __syncthreads();
    float linv = 1.0f / lrow[row];
    int b = bh >> 4, hh = bh & 15;
    int q = qblk * 64 + row;
#pragma unroll
    for (int j = 0; j < 16; ++j)
        ctx[((size_t)(b * T + q)) * D + hh * 64 + seg * 16 + j] = Oacc[j] * linv;
}

// ---------------------------------------------------------------------------
// Persistent GRU recurrence, SELF-VALIDATING DATA protocol:
//  - every cross-block value is an atomic u64 (fp32 bits | epoch<<32),
//    stored ONCE with a relaxed agent-scope store (bypasses per-XCD L2).
//  - consumers poll the data pairs directly (retry only stale ones):
//    no flags, no vmcnt drains, no fences, no barriers.
//  - h and hp are parity double-buffered: epoch e lives in buffer e&1.
//    Program order per block guarantees no producer can be 2 epochs ahead
//    on the same parity while a consumer still polls (proof: to start
//    phaseA(g+2) a block consumed every block's phaseA(g+1) output, which
//    follows their phaseB(g) reads).
// Pair layout: pairs[chain][par][row0..3][dim0..1023], 8 B each.
// ---------------------------------------------------------------------------
__global__ __launch_bounds__(256, 1) void gru_persistent(
    const float* __restrict__ w_hh, const float* __restrict__ b_hh,
    const float* __restrict__ gate_w,
    const float* __restrict__ gi, const float* __restrict__ ga,
    const float* __restrict__ attn, float* __restrict__ out,
    unsigned long long* __restrict__ hPairs,
    unsigned long long* __restrict__ hpPairs)
{
    extern __shared__ float lds[];   // [0,32768): weights; then 4*STG_PITCH stage
    float* sh = lds + 32768;
    const int tid = threadIdx.x;
    const int chain = blockIdx.x & 1;
    const int pos = blockIdx.x >> 1;            // 0..127
    const int d0 = pos * DIMS_PER_BLK;

    // resident weights: rows 0..7 w_r, 8..15 w_z, 16..23 w_n, 24..31 gate_wL
#pragma unroll 4
    for (int r = 0; r < 32; ++r) {
        int which = r >> 3, j = r & 7;
        const float* src = (which < 3)
            ? (w_hh + (size_t)(which * D + d0 + j) * D)
            : (gate_w + (size_t)(d0 + j) * (2 * D));
        float4 v = *(const float4*)(src + tid * 4);
        *(float4*)(&lds[(size_t)r * 1024 + tid * 4]) = v;
    }

    const int grp = tid >> 3, kp = tid & 7;
    const int bl = grp & 3, j = grp >> 2;       // batch-in-chain, dim-in-block
    const int bg = chain * 4 + bl;              // global batch row
    const int d = d0 + j;
    const float* wr = lds + (0 * 8 + j) * 1024;
    const float* wz = lds + (8 + j) * 1024;
    const float* wn = lds + (16 + j) * 1024;
    const float* wg = lds + (24 + j) * 1024;
    const float* hrow_sh = sh + bl * STG_PITCH;

    // chain-local pair regions: [par][4][1024]
    unsigned long long* hC  = hPairs  + (size_t)chain * 2 * 4096;
    unsigned long long* hpC = hpPairs + (size_t)chain * 2 * 4096;

    const float bhr = b_hh[d], bhz = b_hh[D + d], bhn = b_hh[2 * D + d];

    float hpv = 0.0f;                 // own-dim h' carried A->B in register

    // poll-and-stage: wait until all 16 of this thread's pairs carry EPOCH,
    // then deposit values into the LDS staging tile.
#define POLL_AND_STAGE(PSRC, EPOCH)                                           \
    {                                                                         \
        const unsigned long long* ps_ = (PSRC);                               \
        const unsigned ep_ = (EPOCH);                                         \
        unsigned vx_[16]; unsigned vy_[16];                                   \
        _Pragma("unroll")                                                     \
        for (int q = 0; q < 16; ++q) vy_[q] = ep_ ^ 0x80000000u;              \
        for (;;) {                                                            \
            bool all_ = true;                                                 \
            _Pragma("unroll")                                                 \
            for (int q = 0; q < 16; ++q) {                                    \
                if (vy_[q] != ep_) {                                          \
                    unsigned long long pk_ = __hip_atomic_load(               \
                        ps_ + q * 256 + tid, __ATOMIC_RELAXED,                \
                        __HIP_MEMORY_SCOPE_AGENT);                            \
                    vx_[q] = (unsigned)pk_;                                   \
                    vy_[q] = (unsigned)(pk_ >> 32);                           \
                    if (vy_[q] != ep_) all_ = false;                          \
                }                                                             \
            }                                                                 \
            if (all_) break;                                                  \
        }                                                                     \
        __syncthreads();   /* prior phase done reading sh */                  \
        _Pragma("unroll")                                                     \
        for (int q = 0; q < 16; ++q) {                                        \
            int w = q * 256 + tid;                                            \
            sh[(w >> 10) * STG_PITCH + (w & 1023)] = __uint_as_float(vx_[q]); \
        }                                                                     \
        __syncthreads();                                                      \
    }

    unsigned g = 0;                    // global inner step 0..4095
    for (int t = 0; t < T; ++t) {
        const float* gib = gi + ((size_t)bg * T + t) * (3 * D);
        const float gav_a = ga[((size_t)bg * T + t) * D + d];
        const float av = attn[((size_t)bg * T + t) * D + d];
        for (int s = 0; s < NSTEPS; ++s, ++g) {
            const unsigned epNew = g + 1;
            // ---- phase A: stage h (epoch g, parity g&1), gh = h @ w_hh^T
            POLL_AND_STAGE(hC + (size_t)(g & 1) * 4096, g)
            float ar = 0.0f, az = 0.0f, an = 0.0f;
#pragma unroll 8
            for (int m = 0; m < 32; ++m) {
                int kk = (kp + 8 * m) * 4;
                float4 hv = *(const float4*)(hrow_sh + kk);
                float4 w0 = *(const float4*)(wr + kk);
                float4 w1 = *(const float4*)(wz + kk);
                float4 w2 = *(const float4*)(wn + kk);
                ar += hv.x * w0.x + hv.y * w0.y + hv.z * w0.z + hv.w * w0.w;
                az += hv.x * w1.x + hv.y * w1.y + hv.z * w1.z + hv.w * w1.w;
                an += hv.x * w2.x + hv.y * w2.y + hv.z * w2.z + hv.w * w2.w;
            }
#pragma unroll
            for (int off = 1; off < 8; off <<= 1) {
                ar += __shfl_xor(ar, off);
                az += __shfl_xor(az, off);
                an += __shfl_xor(an, off);
            }
            if (kp == 0) {
                float r_ = sigmoidf_(gib[d] + ar + bhr);
                float z_ = sigmoidf_(gib[D + d] + az + bhz);
                float n_ = tanhf(gib[2 * D + d] + r_ * (an + bhn));
                float ho = hrow_sh[d];
                hpv = (1.0f - z_) * n_ + z_ * ho;
                unsigned long long pkt = (unsigned long long)__float_as_uint(hpv)
                                       | ((unsigned long long)epNew << 32);
                __hip_atomic_store(hpC + (size_t)(epNew & 1) * 4096 + bl * 1024 + d,
                                   pkt, __ATOMIC_RELAXED, __HIP_MEMORY_SCOPE_AGENT);
            }

            // ---- phase B: stage hp (epoch g+1), g = sigmoid(hp @ gwL^T + ga)
            POLL_AND_STAGE(hpC + (size_t)(epNew & 1) * 4096, epNew)
            float ag = 0.0f;
#pragma unroll 8
            for (int m = 0; m < 32; ++m) {
                int kk = (kp + 8 * m) * 4;
                float4 hv = *(const float4*)(hrow_sh + kk);
                float4 wv = *(const float4*)(wg + kk);
                ag += hv.x * wv.x + hv.y * wv.y + hv.z * wv.z + hv.w * wv.w;
            }
#pragma unroll
            for (int off = 1; off < 8; off <<= 1) ag += __shfl_xor(ag, off);
            if (kp == 0) {
                float gt = sigmoidf_(ag + gav_a);
                float hn = gt * hpv + (1.0f - gt) * av;
                unsigned long long pkt = (unsigned long long)__float_as_uint(hn)
                                       | ((unsigned long long)epNew << 32);
                __hip_atomic_store(hC + (size_t)(epNew & 1) * 4096 + bl * 1024 + d,
                                   pkt, __ATOMIC_RELAXED, __HIP_MEMORY_SCOPE_AGENT);
                if (s == NSTEPS - 1) out[((size_t)bg * T + t) * D + d] = hn;
            }
        }
    }
#undef POLL_AND_STAGE
}

// ---------------------------------------------------------------------------
extern "C" void kernel_launch(void* const* d_in, const int* in_sizes, int n_in,
                              void* d_out, int out_size, void* d_ws, size_t ws_size,
                              hipStream_t stream)
{
    const float* x          = (const float*)d_in[0];
    const float* in_proj_w  = (const float*)d_in[1];
    const float* in_proj_b  = (const float*)d_in[2];
    const float* out_proj_w = (const float*)d_in[3];
    const float* out_proj_b = (const float*)d_in[4];
    const float* w_ih       = (const float*)d_in[5];
    const float* w_hh       = (const float*)d_in[6];
    const float* b_ih       = (const float*)d_in[7];
    const float* b_hh       = (const float*)d_in[8];
    const float* gate_w     = (const float*)d_in[9];
    const float* gate_b     = (const float*)d_in[10];
    float* out = (float*)d_out;

    float* ws = (float*)d_ws;
    const size_t S1 = (size_t)B * H * T * DH;   // 8,388,608 floats
    float* qb   = ws;
    float* kb   = ws + S1;
    float* vb   = ws + 2 * S1;
    float* ctx  = ws + 3 * S1;
    float* attn = ws + 4 * S1;
    float* ga   = ws + 5 * S1;
    float* gi   = ws;                           // overlaps q/k/v
    // pair buffers: h = 2 chains x 2 par x 4096 pairs, hp likewise (256 KB)
    unsigned long long* hPairs  = (unsigned long long*)(ws + 6 * S1);
    unsigned long long* hpPairs = hPairs + (size_t)NCHAIN * 2 * 4096;

    dim3 blk(256);

    gemm_kernel<1><<<dim3(128, 48), blk, 0, stream>>>(
        x, in_proj_w, in_proj_b, nullptr, B * T, 3 * D, D, D, 0, qb, kb, vb);
    attn_kernel<<<dim3(2048), blk, 0, stream>>>(qb, kb, vb, ctx);
    gemm_kernel<0><<<dim3(128, 16), blk, 0, stream>>>(
        ctx, out_proj_w, out_proj_b, attn, B * T, D, D, D, 0,
        nullptr, nullptr, nullptr);
    gemm_kernel<0><<<dim3(128, 16), blk, 0, stream>>>(
        attn, gate_w, gate_b, ga, B * T, D, D, 2 * D, D,
        nullptr, nullptr, nullptr);
    gemm_kernel<0><<<dim3(128, 48), blk, 0, stream>>>(
        x, w_ih, b_ih, gi, B * T, 3 * D, D, D, 0,
        nullptr, nullptr, nullptr);

    // zero both pair buffers every launch: epoch words -> 0, and the initial
    // h (epoch 0, parity 0) is exactly (0.0f, 0) == all-zero bytes.
    hipMemsetAsync(hPairs, 0,
                   (size_t)2 * NCHAIN * 2 * 4096 * sizeof(unsigned long long),
                   stream);

    const int LDS_BYTES = (32 * 1024 + 4 * STG_PITCH) * 4;   // 147,584
    static bool attr_done = false;
    if (!attr_done) {
        hipFuncSetAttribute((const void*)gru_persistent,
                            hipFuncAttributeMaxDynamicSharedMemorySize, LDS_BYTES);
        attr_done = true;
    }
    gru_persistent<<<dim3(NCHAIN * NBLK_CHAIN), blk, LDS_BYTES, stream>>>(
        w_hh, b_hh, gate_w, gi, ga, attn, out, hPairs, hpPairs);
}

// Round 6
// 53567.114 us; speedup vs baseline: 1.3039x; 1.3039x over previous
//
#include <hip/hip_runtime.h>
#include <hip/hip_bf16.h>
#include <math.h>
#include <stdint.h>

#define B 8
#define T 1024
#define D 1024
#define H 16
#define DH 64
#define NSTEPS 4

#define NCHAIN 2            // batch split into 2 independent chains of 4 rows
#define NBLK_CHAIN 128      // blocks per chain
#define DIMS_PER_BLK 8      // 128 * 8 = 1024 dims

#define STG_PITCH 1184      // per-row staging pitch: 32 kp-slices * 36 words + pad
#define FLAG_STRIDE 16      // flags 64B apart (own cache line each)

__device__ __forceinline__ float sigmoidf_(float x) { return 1.0f / (1.0f + expf(-x)); }

// bf16 round-to-nearest-even, returned in low 16 bits
__device__ __forceinline__ unsigned bf16rne(float f) {
    unsigned x = __float_as_uint(f);
    return (x + 0x7FFFu + ((x >> 16) & 1u)) >> 16;
}
// unpack u32 = bf0 | bf1<<16 into two f32
#define UNPK(u, f0, f1)                                                       \
    { f0 = __uint_as_float((u) << 16); f1 = __uint_as_float((u) & 0xFFFF0000u); }

// ---------------------------------------------------------------------------
// Generic tiled fp32 GEMM: C[M,N] = A[M,K] @ W[N,K]^T + bias[N]
// MODE 0: C[m*N + n];  MODE 1: qkv scatter to q/k/v [B*H, T, DH]
// ---------------------------------------------------------------------------
template <int MODE>
__global__ __launch_bounds__(256) void gemm_kernel(
    const float* __restrict__ A, const float* __restrict__ W,
    const float* __restrict__ bias, float* __restrict__ C,
    int M, int N, int K, int ldw, int koff,
    float* __restrict__ qb, float* __restrict__ kb, float* __restrict__ vb)
{
    __shared__ float As[32][68];
    __shared__ float Ws[32][68];
    const int m0 = blockIdx.x * 64, n0 = blockIdx.y * 64;
    const int tid = threadIdx.x;
    const int tn = tid & 15, tm = tid >> 4;
    float acc[4][4] = {};

    for (int k0 = 0; k0 < K; k0 += 32) {
#pragma unroll
        for (int j = 0; j < 2; ++j) {
            int lin = tid + j * 256;
            int r = lin >> 3, c4 = lin & 7;
            float4 av = *(const float4*)(A + (size_t)(m0 + r) * K + k0 + c4 * 4);
            As[c4 * 4 + 0][r] = av.x; As[c4 * 4 + 1][r] = av.y;
            As[c4 * 4 + 2][r] = av.z; As[c4 * 4 + 3][r] = av.w;
            float4 wv = *(const float4*)(W + (size_t)(n0 + r) * ldw + koff + k0 + c4 * 4);
            Ws[c4 * 4 + 0][r] = wv.x; Ws[c4 * 4 + 1][r] = wv.y;
            Ws[c4 * 4 + 2][r] = wv.z; Ws[c4 * 4 + 3][r] = wv.w;
        }
        __syncthreads();
#pragma unroll
        for (int k = 0; k < 32; ++k) {
            float a_[4], b_[4];
            *(float4*)a_ = *(const float4*)&As[k][tm * 4];
            *(float4*)b_ = *(const float4*)&Ws[k][tn * 4];
#pragma unroll
            for (int i = 0; i < 4; ++i)
#pragma unroll
                for (int j = 0; j < 4; ++j) acc[i][j] += a_[i] * b_[j];
        }
        __syncthreads();
    }

#pragma unroll
    for (int i = 0; i < 4; ++i) {
        int m = m0 + tm * 4 + i;
#pragma unroll
        for (int j = 0; j < 4; ++j) {
            int n = n0 + tn * 4 + j;
            float v = acc[i][j] + bias[n];
            if (MODE == 0) {
                C[(size_t)m * N + n] = v;
            } else {
                int which = n >> 10;
                int hh = (n & 1023) >> 6;
                int dh = n & 63;
                int b = m >> 10, t = m & 1023;
                float* dst = (which == 0) ? qb : ((which == 1) ? kb : vb);
                dst[(((size_t)(b * H + hh)) * T + t) * DH + dh] = v;
            }
        }
    }
}

// ---------------------------------------------------------------------------
// Flash attention fp32 (unchanged)
// ---------------------------------------------------------------------------
__global__ __launch_bounds__(256) void attn_kernel(
    const float* __restrict__ qb, const float* __restrict__ kb,
    const float* __restrict__ vb, float* __restrict__ ctx)
{
    __shared__ float Qs[64][65];
    __shared__ float Ks[64][65];
    __shared__ float Vs[64][65];
    __shared__ float mrow[64], lrow[64], srow[64];
    __shared__ float tred[64][4];

    const int tid = threadIdx.x;
    const int row = tid & 63, seg = tid >> 6;
    const int bx = blockIdx.x;
    const int qblk = bx & 15;
    const int bh = bx >> 4;
    const float* qp = qb + (size_t)bh * T * DH;
    const float* kp = kb + (size_t)bh * T * DH;
    const float* vp = vb + (size_t)bh * T * DH;

#pragma unroll
    for (int i = 0; i < 4; ++i) {
        int lin = tid + i * 256;
        int r = lin >> 4, c4 = lin & 15;
        float4 v = *(const float4*)(qp + (size_t)(qblk * 64 + r) * DH + c4 * 4);
        Qs[r][c4 * 4 + 0] = v.x; Qs[r][c4 * 4 + 1] = v.y;
        Qs[r][c4 * 4 + 2] = v.z; Qs[r][c4 * 4 + 3] = v.w;
    }
    if (tid < 64) { mrow[tid] = -3.0e38f; lrow[tid] = 0.0f; }

    float Oacc[16];
#pragma unroll
    for (int j = 0; j < 16; ++j) Oacc[j] = 0.0f;

    for (int kt = 0; kt < 16; ++kt) {
        __syncthreads();
#pragma unroll
        for (int i = 0; i < 4; ++i) {
            int lin = tid + i * 256;
            int r = lin >> 4, c4 = lin & 15;
            float4 kv = *(const float4*)(kp + (size_t)(kt * 64 + r) * DH + c4 * 4);
            Ks[r][c4 * 4 + 0] = kv.x; Ks[r][c4 * 4 + 1] = kv.y;
            Ks[r][c4 * 4 + 2] = kv.z; Ks[r][c4 * 4 + 3] = kv.w;
            float4 vv = *(const float4*)(vp + (size_t)(kt * 64 + r) * DH + c4 * 4);
            Vs[r][c4 * 4 + 0] = vv.x; Vs[r][c4 * 4 + 1] = vv.y;
            Vs[r][c4 * 4 + 2] = vv.z; Vs[r][c4 * 4 + 3] = vv.w;
        }
        __syncthreads();

        float sacc[16];
#pragma unroll
        for (int j = 0; j < 16; ++j) sacc[j] = 0.0f;
        for (int k = 0; k < 64; ++k) {
            float qv = Qs[row][k];
#pragma unroll
            for (int j = 0; j < 16; ++j) sacc[j] += qv * Ks[seg * 16 + j][k];
        }
        float tmax = -3.0e38f;
#pragma unroll
        for (int j = 0; j < 16; ++j) { sacc[j] *= 0.125f; tmax = fmaxf(tmax, sacc[j]); }
        tred[row][seg] = tmax;
        __syncthreads();
        if (seg == 0) {
            float mt = fmaxf(fmaxf(tred[row][0], tred[row][1]),
                             fmaxf(tred[row][2], tred[row][3]));
            float mo = mrow[row];
            float mn = fmaxf(mo, mt);
            srow[row] = expf(mo - mn);
            mrow[row] = mn;
        }
        __syncthreads();
        float mn = mrow[row], sc = srow[row];
        float psum = 0.0f;
#pragma unroll
        for (int j = 0; j < 16; ++j) {
            float p = expf(sacc[j] - mn);
            Ks[row][seg * 16 + j] = p;
            psum += p;
        }
        tred[row][seg] = psum;
#pragma unroll
        for (int j = 0; j < 16; ++j) Oacc[j] *= sc;
        __syncthreads();
        if (seg == 0)
            lrow[row] = lrow[row] * sc +
                        (tred[row][0] + tred[row][1] + tred[row][2] + tred[row][3]);
        for (int kj = 0; kj < 64; ++kj) {
            float pv = Ks[row][kj];
#pragma unroll
            for (int j = 0; j < 16; ++j) Oacc[j] += pv * Vs[kj][seg * 16 + j];
        }
    }
    __syncthreads();
    float linv = 1.0f / lrow[row];
    int b = bh >> 4, hh = bh & 15;
    int q = qblk * 64 + row;
#pragma unroll
    for (int j = 0; j < 16; ++j)
        ctx[((size_t)(b * T + q)) * D + hh * 64 + seg * 16 + j] = Oacc[j] * linv;
}

// ---------------------------------------------------------------------------
// Persistent GRU recurrence. R4's distributed-flag protocol (best measured)
// + register-resident bf16 weights (the dot loop was LDS-issue-bound):
//   thread = (j = tid>>5 in 0..7, kp = tid&31): holds rows {r,z,n,gate}[d0+j],
//   k-slice [kp*32, kp*32+32) as 64 packed-bf16 u32 VGPRs.
//   h/hp staged in LDS at pitch 36 words per kp-slice (no 32-way banks).
//   Partial dots reduced over kp via __shfl_xor (offsets 1..16 stay in the
//   32-lane half-wave); lane kp==0 finalizes 4 batch rows and stores.
// ---------------------------------------------------------------------------
__global__ __launch_bounds__(256, 1) void gru_persistent(
    const float* __restrict__ w_hh, const float* __restrict__ b_hh,
    const float* __restrict__ gate_w,
    const float* __restrict__ gi, const float* __restrict__ ga,
    const float* __restrict__ attn, float* __restrict__ out,
    float* __restrict__ hbuf, float* __restrict__ hpbuf,
    unsigned* __restrict__ flags)
{
    extern __shared__ float sh[];               // staging: 4 rows * STG_PITCH
    const int tid = threadIdx.x;
    const int chain = blockIdx.x & 1;
    const int pos = blockIdx.x >> 1;            // 0..127
    const int d0 = pos * DIMS_PER_BLK;
    const int kp = tid & 31, jj = tid >> 5;     // k-slice, dim-in-block
    const int d = d0 + jj;

    // ---- load + pack resident weights into VGPRs (bf16 RNE)
    unsigned wpk[4][16];
#pragma unroll
    for (int tt = 0; tt < 4; ++tt) {
        const float* src = (tt < 3) ? (w_hh + ((size_t)(tt * D) + d) * D)
                                    : (gate_w + (size_t)d * (2 * D));
#pragma unroll
        for (int c = 0; c < 8; ++c) {
            float4 v = *(const float4*)(src + kp * 32 + c * 4);
            wpk[tt][c * 2]     = bf16rne(v.x) | (bf16rne(v.y) << 16);
            wpk[tt][c * 2 + 1] = bf16rne(v.z) | (bf16rne(v.w) << 16);
        }
    }
    const float bhr = b_hh[d], bhz = b_hh[D + d], bhn = b_hh[2 * D + d];
    const int hidx = ((d >> 5) * 36) + (((d >> 2) & 7) * 4) + (d & 3);

    unsigned* flagbase = flags + (size_t)chain * NBLK_CHAIN * FLAG_STRIDE;
    const int s0 = tid >> 3;                    // first of this thread's 4 sources
    const float* hsrc  = hbuf  + (size_t)chain * 4 * D;
    const float* hpsrc = hpbuf + (size_t)chain * 4 * D;

    unsigned bar = 0;                           // completed-phase epoch

#define POLL_AND_STAGE(SRC)                                                   \
    {                                                                         \
        for (;;) {                                                            \
            unsigned a0 = __hip_atomic_load(flagbase + (s0     ) * FLAG_STRIDE,\
                              __ATOMIC_RELAXED, __HIP_MEMORY_SCOPE_AGENT);    \
            unsigned a1 = __hip_atomic_load(flagbase + (s0 + 32) * FLAG_STRIDE,\
                              __ATOMIC_RELAXED, __HIP_MEMORY_SCOPE_AGENT);    \
            unsigned a2 = __hip_atomic_load(flagbase + (s0 + 64) * FLAG_STRIDE,\
                              __ATOMIC_RELAXED, __HIP_MEMORY_SCOPE_AGENT);    \
            unsigned a3 = __hip_atomic_load(flagbase + (s0 + 96) * FLAG_STRIDE,\
                              __ATOMIC_RELAXED, __HIP_MEMORY_SCOPE_AGENT);    \
            if (a0 >= bar && a1 >= bar && a2 >= bar && a3 >= bar) break;      \
        }                                                                     \
        float r_[16];                                                         \
        _Pragma("unroll")                                                     \
        for (int q = 0; q < 16; ++q)                                          \
            r_[q] = __hip_atomic_load((SRC) + q * 256 + tid,                  \
                        __ATOMIC_RELAXED, __HIP_MEMORY_SCOPE_AGENT);          \
        _Pragma("unroll")                                                     \
        for (int q = 0; q < 16; ++q) {                                        \
            int w = q * 256 + tid;                                            \
            int bl_ = w >> 10, k_ = w & 1023;                                 \
            sh[bl_ * STG_PITCH + (k_ >> 5) * 36 + ((k_ >> 2) & 7) * 4 +       \
               (k_ & 3)] = r_[q];                                             \
        }                                                                     \
        __syncthreads();                                                      \
    }

    for (int t = 0; t < T; ++t) {
        // per-t inputs for the finalize lanes (issued early; latency hides
        // under poll+stage+dot)
        float giR[4], giZ[4], giN[4], gav[4], av[4];
        if (kp == 0) {
#pragma unroll
            for (int bl = 0; bl < 4; ++bl) {
                const size_t base = (size_t)(chain * 4 + bl) * T + t;
                const float* gib = gi + base * (3 * D);
                giR[bl] = gib[d];
                giZ[bl] = gib[D + d];
                giN[bl] = gib[2 * D + d];
                gav[bl] = ga[base * D + d];
                av[bl]  = attn[base * D + d];
            }
        }
        for (int s = 0; s < NSTEPS; ++s) {
            // ================= phase A: gh = h @ w_hh^T =================
            POLL_AND_STAGE(hsrc)
            float ar[4] = {0, 0, 0, 0}, az_[4] = {0, 0, 0, 0}, an_[4] = {0, 0, 0, 0};
#pragma unroll
            for (int kc = 0; kc < 8; ++kc) {
                float wr0, wr1, wr2, wr3, wz0, wz1, wz2, wz3, wn0, wn1, wn2, wn3;
                UNPK(wpk[0][kc * 2],     wr0, wr1) UNPK(wpk[0][kc * 2 + 1], wr2, wr3)
                UNPK(wpk[1][kc * 2],     wz0, wz1) UNPK(wpk[1][kc * 2 + 1], wz2, wz3)
                UNPK(wpk[2][kc * 2],     wn0, wn1) UNPK(wpk[2][kc * 2 + 1], wn2, wn3)
                const int ha = kp * 36 + kc * 4;
#pragma unroll
                for (int bl = 0; bl < 4; ++bl) {
                    float4 hv = *(const float4*)&sh[bl * STG_PITCH + ha];
                    ar[bl]  += hv.x * wr0 + hv.y * wr1 + hv.z * wr2 + hv.w * wr3;
                    az_[bl] += hv.x * wz0 + hv.y * wz1 + hv.z * wz2 + hv.w * wz3;
                    an_[bl] += hv.x * wn0 + hv.y * wn1 + hv.z * wn2 + hv.w * wn3;
                }
            }
#pragma unroll
            for (int off = 1; off < 32; off <<= 1) {
#pragma unroll
                for (int bl = 0; bl < 4; ++bl) {
                    ar[bl]  += __shfl_xor(ar[bl], off);
                    az_[bl] += __shfl_xor(az_[bl], off);
                    an_[bl] += __shfl_xor(an_[bl], off);
                }
            }
            if (kp == 0) {
#pragma unroll
                for (int bl = 0; bl < 4; ++bl) {
                    float r_ = sigmoidf_(giR[bl] + ar[bl] + bhr);
                    float z_ = sigmoidf_(giZ[bl] + az_[bl] + bhz);
                    float n_ = tanhf(giN[bl] + r_ * (an_[bl] + bhn));
                    float ho = sh[bl * STG_PITCH + hidx];
                    float hp_ = (1.0f - z_) * n_ + z_ * ho;
                    __hip_atomic_store(
                        hpbuf + (size_t)(chain * 4 + bl) * D + d, hp_,
                        __ATOMIC_RELAXED, __HIP_MEMORY_SCOPE_AGENT);
                }
            }
            asm volatile("s_waitcnt vmcnt(0)" ::: "memory");
            __syncthreads();
            ++bar;
            if (tid == 0)
                __hip_atomic_store(flagbase + pos * FLAG_STRIDE, bar,
                                   __ATOMIC_RELAXED, __HIP_MEMORY_SCOPE_AGENT);

            // ============ phase B: g = sigmoid(hp @ gwL^T + ga) ==========
            POLL_AND_STAGE(hpsrc)
            float ag[4] = {0, 0, 0, 0};
#pragma unroll
            for (int kc = 0; kc < 8; ++kc) {
                float wg0, wg1, wg2, wg3;
                UNPK(wpk[3][kc * 2], wg0, wg1) UNPK(wpk[3][kc * 2 + 1], wg2, wg3)
                const int ha = kp * 36 + kc * 4;
#pragma unroll
                for (int bl = 0; bl < 4; ++bl) {
                    float4 hv = *(const float4*)&sh[bl * STG_PITCH + ha];
                    ag[bl] += hv.x * wg0 + hv.y * wg1 + hv.z * wg2 + hv.w * wg3;
                }
            }
#pragma unroll
            for (int off = 1; off < 32; off <<= 1) {
#pragma unroll
                for (int bl = 0; bl < 4; ++bl) ag[bl] += __shfl_xor(ag[bl], off);
            }
            if (kp == 0) {
#pragma unroll
                for (int bl = 0; bl < 4; ++bl) {
                    float g = sigmoidf_(ag[bl] + gav[bl]);
                    float hpd = sh[bl * STG_PITCH + hidx];
                    float hn = g * hpd + (1.0f - g) * av[bl];
                    __hip_atomic_store(
                        hbuf + (size_t)(chain * 4 + bl) * D + d, hn,
                        __ATOMIC_RELAXED, __HIP_MEMORY_SCOPE_AGENT);
                    if (s == NSTEPS - 1)
                        out[((size_t)(chain * 4 + bl) * T + t) * D + d] = hn;
                }
            }
            asm volatile("s_waitcnt vmcnt(0)" ::: "memory");
            __syncthreads();
            ++bar;
            if (tid == 0)
                __hip_atomic_store(flagbase + pos * FLAG_STRIDE, bar,
                                   __ATOMIC_RELAXED, __HIP_MEMORY_SCOPE_AGENT);
        }
    }
#undef POLL_AND_STAGE
}

// ---------------------------------------------------------------------------
extern "C" void kernel_launch(void* const* d_in, const int* in_sizes, int n_in,
                              void* d_out, int out_size, void* d_ws, size_t ws_size,
                              hipStream_t stream)
{
    const float* x          = (const float*)d_in[0];
    const float* in_proj_w  = (const float*)d_in[1];
    const float* in_proj_b  = (const float*)d_in[2];
    const float* out_proj_w = (const float*)d_in[3];
    const float* out_proj_b = (const float*)d_in[4];
    const float* w_ih       = (const float*)d_in[5];
    const float* w_hh       = (const float*)d_in[6];
    const float* b_ih       = (const float*)d_in[7];
    const float* b_hh       = (const float*)d_in[8];
    const float* gate_w     = (const float*)d_in[9];
    const float* gate_b     = (const float*)d_in[10];
    float* out = (float*)d_out;

    float* ws = (float*)d_ws;
    const size_t S1 = (size_t)B * H * T * DH;   // 8,388,608 floats
    float* qb   = ws;
    float* kb   = ws + S1;
    float* vb   = ws + 2 * S1;
    float* ctx  = ws + 3 * S1;
    float* attn = ws + 4 * S1;
    float* ga   = ws + 5 * S1;
    float* gi   = ws;                           // overlaps q/k/v
    float* hbuf  = ws + 6 * S1;
    float* hpbuf = hbuf + B * D;
    unsigned* flags = (unsigned*)(hpbuf + B * D);  // 2 chains *128 flags *64B

    dim3 blk(256);

    gemm_kernel<1><<<dim3(128, 48), blk, 0, stream>>>(
        x, in_proj_w, in_proj_b, nullptr, B * T, 3 * D, D, D, 0, qb, kb, vb);
    attn_kernel<<<dim3(2048), blk, 0, stream>>>(qb, kb, vb, ctx);
    gemm_kernel<0><<<dim3(128, 16), blk, 0, stream>>>(
        ctx, out_proj_w, out_proj_b, attn, B * T, D, D, D, 0,
        nullptr, nullptr, nullptr);
    gemm_kernel<0><<<dim3(128, 16), blk, 0, stream>>>(
        attn, gate_w, gate_b, ga, B * T, D, D, 2 * D, D,
        nullptr, nullptr, nullptr);
    gemm_kernel<0><<<dim3(128, 48), blk, 0, stream>>>(
        x, w_ih, b_ih, gi, B * T, 3 * D, D, D, 0,
        nullptr, nullptr, nullptr);

    // zero h, hp, and flags every launch (graph-replay deterministic)
    hipMemsetAsync(hbuf, 0,
                   (2 * (size_t)B * D) * sizeof(float) +
                   NCHAIN * NBLK_CHAIN * FLAG_STRIDE * sizeof(unsigned),
                   stream);

    // staging needs only 4*STG_PITCH*4 B; request 96 KB to force 1 block/CU
    const int LDS_BYTES = 98304;
    static bool attr_done = false;
    if (!attr_done) {
        hipFuncSetAttribute((const void*)gru_persistent,
                            hipFuncAttributeMaxDynamicSharedMemorySize, LDS_BYTES);
        attr_done = true;
    }
    gru_persistent<<<dim3(NCHAIN * NBLK_CHAIN), blk, LDS_BYTES, stream>>>(
        w_hh, b_hh, gate_w, gi, ga, attn, out, hbuf, hpbuf, flags);
}

// Round 7
// 35489.557 us; speedup vs baseline: 1.9681x; 1.5094x over previous
//
#include <hip/hip_runtime.h>
#include <hip/hip_bf16.h>
#include <math.h>
#include <stdint.h>

#define B 8
#define T 1024
#define D 1024
#define H 16
#define DH 64
#define NSTEPS 4

#define NCHAIN 2            // batch split into 2 independent chains of 4 rows
#define NBLK_CHAIN 128      // blocks per chain
#define DIMS_PER_BLK 8      // 128 * 8 = 1024 dims

#define FLAG_STRIDE 16      // flags 64B apart (own cache line each)

__device__ __forceinline__ float sigmoidf_(float x) { return 1.0f / (1.0f + expf(-x)); }

// bf16 round-to-nearest-even, returned in low 16 bits
__device__ __forceinline__ unsigned bf16rne(float f) {
    unsigned x = __float_as_uint(f);
    return (x + 0x7FFFu + ((x >> 16) & 1u)) >> 16;
}
// unpack u32 = bf0 | bf1<<16 into two f32
#define UNPK(u, f0, f1)                                                       \
    { f0 = __uint_as_float((u) << 16); f1 = __uint_as_float((u) & 0xFFFF0000u); }

// ---------------------------------------------------------------------------
// Generic tiled fp32 GEMM: C[M,N] = A[M,K] @ W[N,K]^T + bias[N]
// MODE 0: C[m*N + n];  MODE 1: qkv scatter to q/k/v [B*H, T, DH]
// ---------------------------------------------------------------------------
template <int MODE>
__global__ __launch_bounds__(256) void gemm_kernel(
    const float* __restrict__ A, const float* __restrict__ W,
    const float* __restrict__ bias, float* __restrict__ C,
    int M, int N, int K, int ldw, int koff,
    float* __restrict__ qb, float* __restrict__ kb, float* __restrict__ vb)
{
    __shared__ float As[32][68];
    __shared__ float Ws[32][68];
    const int m0 = blockIdx.x * 64, n0 = blockIdx.y * 64;
    const int tid = threadIdx.x;
    const int tn = tid & 15, tm = tid >> 4;
    float acc[4][4] = {};

    for (int k0 = 0; k0 < K; k0 += 32) {
#pragma unroll
        for (int j = 0; j < 2; ++j) {
            int lin = tid + j * 256;
            int r = lin >> 3, c4 = lin & 7;
            float4 av = *(const float4*)(A + (size_t)(m0 + r) * K + k0 + c4 * 4);
            As[c4 * 4 + 0][r] = av.x; As[c4 * 4 + 1][r] = av.y;
            As[c4 * 4 + 2][r] = av.z; As[c4 * 4 + 3][r] = av.w;
            float4 wv = *(const float4*)(W + (size_t)(n0 + r) * ldw + koff + k0 + c4 * 4);
            Ws[c4 * 4 + 0][r] = wv.x; Ws[c4 * 4 + 1][r] = wv.y;
            Ws[c4 * 4 + 2][r] = wv.z; Ws[c4 * 4 + 3][r] = wv.w;
        }
        __syncthreads();
#pragma unroll
        for (int k = 0; k < 32; ++k) {
            float a_[4], b_[4];
            *(float4*)a_ = *(const float4*)&As[k][tm * 4];
            *(float4*)b_ = *(const float4*)&Ws[k][tn * 4];
#pragma unroll
            for (int i = 0; i < 4; ++i)
#pragma unroll
                for (int j = 0; j < 4; ++j) acc[i][j] += a_[i] * b_[j];
        }
        __syncthreads();
    }

#pragma unroll
    for (int i = 0; i < 4; ++i) {
        int m = m0 + tm * 4 + i;
#pragma unroll
        for (int j = 0; j < 4; ++j) {
            int n = n0 + tn * 4 + j;
            float v = acc[i][j] + bias[n];
            if (MODE == 0) {
                C[(size_t)m * N + n] = v;
            } else {
                int which = n >> 10;
                int hh = (n & 1023) >> 6;
                int dh = n & 63;
                int b = m >> 10, t = m & 1023;
                float* dst = (which == 0) ? qb : ((which == 1) ? kb : vb);
                dst[(((size_t)(b * H + hh)) * T + t) * DH + dh] = v;
            }
        }
    }
}

// ---------------------------------------------------------------------------
// Flash attention fp32 (unchanged)
// ---------------------------------------------------------------------------
__global__ __launch_bounds__(256) void attn_kernel(
    const float* __restrict__ qb, const float* __restrict__ kb,
    const float* __restrict__ vb, float* __restrict__ ctx)
{
    __shared__ float Qs[64][65];
    __shared__ float Ks[64][65];
    __shared__ float Vs[64][65];
    __shared__ float mrow[64], lrow[64], srow[64];
    __shared__ float tred[64][4];

    const int tid = threadIdx.x;
    const int row = tid & 63, seg = tid >> 6;
    const int bx = blockIdx.x;
    const int qblk = bx & 15;
    const int bh = bx >> 4;
    const float* qp = qb + (size_t)bh * T * DH;
    const float* kp = kb + (size_t)bh * T * DH;
    const float* vp = vb + (size_t)bh * T * DH;

#pragma unroll
    for (int i = 0; i < 4; ++i) {
        int lin = tid + i * 256;
        int r = lin >> 4, c4 = lin & 15;
        float4 v = *(const float4*)(qp + (size_t)(qblk * 64 + r) * DH + c4 * 4);
        Qs[r][c4 * 4 + 0] = v.x; Qs[r][c4 * 4 + 1] = v.y;
        Qs[r][c4 * 4 + 2] = v.z; Qs[r][c4 * 4 + 3] = v.w;
    }
    if (tid < 64) { mrow[tid] = -3.0e38f; lrow[tid] = 0.0f; }

    float Oacc[16];
#pragma unroll
    for (int j = 0; j < 16; ++j) Oacc[j] = 0.0f;

    for (int kt = 0; kt < 16; ++kt) {
        __syncthreads();
#pragma unroll
        for (int i = 0; i < 4; ++i) {
            int lin = tid + i * 256;
            int r = lin >> 4, c4 = lin & 15;
            float4 kv = *(const float4*)(kp + (size_t)(kt * 64 + r) * DH + c4 * 4);
            Ks[r][c4 * 4 + 0] = kv.x; Ks[r][c4 * 4 + 1] = kv.y;
            Ks[r][c4 * 4 + 2] = kv.z; Ks[r][c4 * 4 + 3] = kv.w;
            float4 vv = *(const float4*)(vp + (size_t)(kt * 64 + r) * DH + c4 * 4);
            Vs[r][c4 * 4 + 0] = vv.x; Vs[r][c4 * 4 + 1] = vv.y;
            Vs[r][c4 * 4 + 2] = vv.z; Vs[r][c4 * 4 + 3] = vv.w;
        }
        __syncthreads();

        float sacc[16];
#pragma unroll
        for (int j = 0; j < 16; ++j) sacc[j] = 0.0f;
        for (int k = 0; k < 64; ++k) {
            float qv = Qs[row][k];
#pragma unroll
            for (int j = 0; j < 16; ++j) sacc[j] += qv * Ks[seg * 16 + j][k];
        }
        float tmax = -3.0e38f;
#pragma unroll
        for (int j = 0; j < 16; ++j) { sacc[j] *= 0.125f; tmax = fmaxf(tmax, sacc[j]); }
        tred[row][seg] = tmax;
        __syncthreads();
        if (seg == 0) {
            float mt = fmaxf(fmaxf(tred[row][0], tred[row][1]),
                             fmaxf(tred[row][2], tred[row][3]));
            float mo = mrow[row];
            float mn = fmaxf(mo, mt);
            srow[row] = expf(mo - mn);
            mrow[row] = mn;
        }
        __syncthreads();
        float mn = mrow[row], sc = srow[row];
        float psum = 0.0f;
#pragma unroll
        for (int j = 0; j < 16; ++j) {
            float p = expf(sacc[j] - mn);
            Ks[row][seg * 16 + j] = p;
            psum += p;
        }
        tred[row][seg] = psum;
#pragma unroll
        for (int j = 0; j < 16; ++j) Oacc[j] *= sc;
        __syncthreads();
        if (seg == 0)
            lrow[row] = lrow[row] * sc +
                        (tred[row][0] + tred[row][1] + tred[row][2] + tred[row][3]);
        for (int kj = 0; kj < 64; ++kj) {
            float pv = Ks[row][kj];
#pragma unroll
            for (int j = 0; j < 16; ++j) Oacc[j] += pv * Vs[kj][seg * 16 + j];
        }
    }
    __syncthreads();
    float linv = 1.0f / lrow[row];
    int b = bh >> 4, hh = bh & 15;
    int q = qblk * 64 + row;
#pragma unroll
    for (int j = 0; j < 16; ++j)
        ctx[((size_t)(b * T + q)) * D + hh * 64 + seg * 16 + j] = Oacc[j] * linv;
}

// ---------------------------------------------------------------------------
// Persistent GRU recurrence. R4's distributed-flag protocol (best measured)
// + fixed register-weight dot:
//   thread = (jj = tid>>5 in 0..7, kp = tid&31): holds rows {r,z,n,gate}[d0+jj]
//   for k-slice {c*128 + kp*4 + i} as 64 packed-bf16 u32 VGPRs.
//   h/hp staged LINEARLY in LDS sh[bl*1024+k]; dot reads are b128 at
//   consecutive-16B-per-lane (conflict-free), jj halves broadcast.
//   Reduction over 32 kp lanes via LDS transpose scratch (pitch 36),
//   96-thread row-reduce, 32-thread finalize (f -> jj=f>>2, bl=f&3).
// ---------------------------------------------------------------------------
__global__ __launch_bounds__(256, 1) void gru_persistent(
    const float* __restrict__ w_hh, const float* __restrict__ b_hh,
    const float* __restrict__ gate_w,
    const float* __restrict__ gi, const float* __restrict__ ga,
    const float* __restrict__ attn, float* __restrict__ out,
    float* __restrict__ hbuf, float* __restrict__ hpbuf,
    unsigned* __restrict__ flags)
{
    extern __shared__ float lds[];
    float* sh   = lds;                 // [4][1024] staged h or hp
    float* redA = lds + 4096;          // [96][36] transpose scratch
    float* red2 = lds + 4096 + 96 * 36;// [96] row sums

    const int tid = threadIdx.x;
    const int chain = blockIdx.x & 1;
    const int pos = blockIdx.x >> 1;            // 0..127
    const int d0 = pos * DIMS_PER_BLK;
    const int kp = tid & 31, jj = tid >> 5;
    const int d = d0 + jj;

    // ---- resident weights in VGPRs (packed bf16), k = c*128 + kp*4 + {0..3}
    unsigned wpk[4][16];
#pragma unroll
    for (int tt = 0; tt < 4; ++tt) {
        const float* src = (tt < 3) ? (w_hh + ((size_t)(tt * D) + d) * D)
                                    : (gate_w + (size_t)d * (2 * D));
#pragma unroll
        for (int c = 0; c < 8; ++c) {
            float4 v = *(const float4*)(src + c * 128 + kp * 4);
            wpk[tt][c * 2]     = bf16rne(v.x) | (bf16rne(v.y) << 16);
            wpk[tt][c * 2 + 1] = bf16rne(v.z) | (bf16rne(v.w) << 16);
        }
    }

    // finalize-thread constants (tid < 32: jj2 = tid>>2, bl = tid&3)
    float bfr = 0.0f, bfz = 0.0f, bfn = 0.0f;
    int fd = 0, fbg = 0;
    if (tid < 32) {
        int jj2 = tid >> 2, bl = tid & 3;
        fd = d0 + jj2;
        fbg = chain * 4 + bl;
        bfr = b_hh[fd]; bfz = b_hh[D + fd]; bfn = b_hh[2 * D + fd];
    }

    unsigned* flagbase = flags + (size_t)chain * NBLK_CHAIN * FLAG_STRIDE;
    const int s0 = tid >> 3;                    // first of this thread's 4 sources
    const float* hsrc  = hbuf  + (size_t)chain * 4 * D;
    const float* hpsrc = hpbuf + (size_t)chain * 4 * D;

    unsigned bar = 0;                           // completed-phase epoch
    float hpv = 0.0f;                           // finalize threads only

#define POLL_AND_STAGE(SRC)                                                   \
    {                                                                         \
        for (;;) {                                                            \
            unsigned a0 = __hip_atomic_load(flagbase + (s0     ) * FLAG_STRIDE,\
                              __ATOMIC_RELAXED, __HIP_MEMORY_SCOPE_AGENT);    \
            unsigned a1 = __hip_atomic_load(flagbase + (s0 + 32) * FLAG_STRIDE,\
                              __ATOMIC_RELAXED, __HIP_MEMORY_SCOPE_AGENT);    \
            unsigned a2 = __hip_atomic_load(flagbase + (s0 + 64) * FLAG_STRIDE,\
                              __ATOMIC_RELAXED, __HIP_MEMORY_SCOPE_AGENT);    \
            unsigned a3 = __hip_atomic_load(flagbase + (s0 + 96) * FLAG_STRIDE,\
                              __ATOMIC_RELAXED, __HIP_MEMORY_SCOPE_AGENT);    \
            if (a0 >= bar && a1 >= bar && a2 >= bar && a3 >= bar) break;      \
        }                                                                     \
        float r_[16];                                                         \
        _Pragma("unroll")                                                     \
        for (int q = 0; q < 16; ++q)                                          \
            r_[q] = __hip_atomic_load((SRC) + q * 256 + tid,                  \
                        __ATOMIC_RELAXED, __HIP_MEMORY_SCOPE_AGENT);          \
        _Pragma("unroll")                                                     \
        for (int q = 0; q < 16; ++q) sh[q * 256 + tid] = r_[q];               \
        __syncthreads();                                                      \
    }

    for (int t = 0; t < T; ++t) {
        // per-t inputs for the finalize threads
        float giR = 0, giZ = 0, giN = 0, gav = 0, av = 0;
        if (tid < 32) {
            const size_t base = (size_t)fbg * T + t;
            const float* gib = gi + base * (3 * D);
            giR = gib[fd]; giZ = gib[D + fd]; giN = gib[2 * D + fd];
            gav = ga[base * D + fd];
            av  = attn[base * D + fd];
        }
        for (int s = 0; s < NSTEPS; ++s) {
            // ================= phase A: gh = h @ w_hh^T =================
            POLL_AND_STAGE(hsrc)
            {
                float ar[4] = {0, 0, 0, 0}, az[4] = {0, 0, 0, 0}, an[4] = {0, 0, 0, 0};
#pragma unroll
                for (int c = 0; c < 8; ++c) {
                    float wr0, wr1, wr2, wr3, wz0, wz1, wz2, wz3;
                    float wn0, wn1, wn2, wn3;
                    UNPK(wpk[0][c * 2],     wr0, wr1)
                    UNPK(wpk[0][c * 2 + 1], wr2, wr3)
                    UNPK(wpk[1][c * 2],     wz0, wz1)
                    UNPK(wpk[1][c * 2 + 1], wz2, wz3)
                    UNPK(wpk[2][c * 2],     wn0, wn1)
                    UNPK(wpk[2][c * 2 + 1], wn2, wn3)
                    const int ha = c * 128 + kp * 4;
#pragma unroll
                    for (int bl = 0; bl < 4; ++bl) {
                        float4 hv = *(const float4*)&sh[bl * 1024 + ha];
                        ar[bl] += hv.x * wr0 + hv.y * wr1 + hv.z * wr2 + hv.w * wr3;
                        az[bl] += hv.x * wz0 + hv.y * wz1 + hv.z * wz2 + hv.w * wz3;
                        an[bl] += hv.x * wn0 + hv.y * wn1 + hv.z * wn2 + hv.w * wn3;
                    }
                }
#pragma unroll
                for (int bl = 0; bl < 4; ++bl) {
                    redA[(jj * 12 + 0 + bl) * 36 + kp] = ar[bl];
                    redA[(jj * 12 + 4 + bl) * 36 + kp] = az[bl];
                    redA[(jj * 12 + 8 + bl) * 36 + kp] = an[bl];
                }
            }
            __syncthreads();
            if (tid < 96) {
                float4 s4 = {0, 0, 0, 0};
#pragma unroll
                for (int c = 0; c < 8; ++c) {
                    float4 v = *(const float4*)&redA[tid * 36 + c * 4];
                    s4.x += v.x; s4.y += v.y; s4.z += v.z; s4.w += v.w;
                }
                red2[tid] = (s4.x + s4.y) + (s4.z + s4.w);
            }
            __syncthreads();
            if (tid < 32) {
                int jj2 = tid >> 2, bl = tid & 3;
                int base = jj2 * 12 + bl;
                float sr = red2[base], sz = red2[base + 4], sn = red2[base + 8];
                float r_ = sigmoidf_(giR + sr + bfr);
                float z_ = sigmoidf_(giZ + sz + bfz);
                float n_ = tanhf(giN + r_ * (sn + bfn));
                float ho = sh[bl * 1024 + fd];
                hpv = (1.0f - z_) * n_ + z_ * ho;
                __hip_atomic_store(hpbuf + (size_t)fbg * D + fd, hpv,
                                   __ATOMIC_RELAXED, __HIP_MEMORY_SCOPE_AGENT);
            }
            asm volatile("s_waitcnt vmcnt(0)" ::: "memory");
            __syncthreads();
            ++bar;
            if (tid == 0)
                __hip_atomic_store(flagbase + pos * FLAG_STRIDE, bar,
                                   __ATOMIC_RELAXED, __HIP_MEMORY_SCOPE_AGENT);

            // ============ phase B: g = sigmoid(hp @ gwL^T + ga) ==========
            POLL_AND_STAGE(hpsrc)
            {
                float ag[4] = {0, 0, 0, 0};
#pragma unroll
                for (int c = 0; c < 8; ++c) {
                    float wg0, wg1, wg2, wg3;
                    UNPK(wpk[3][c * 2],     wg0, wg1)
                    UNPK(wpk[3][c * 2 + 1], wg2, wg3)
                    const int ha = c * 128 + kp * 4;
#pragma unroll
                    for (int bl = 0; bl < 4; ++bl) {
                        float4 hv = *(const float4*)&sh[bl * 1024 + ha];
                        ag[bl] += hv.x * wg0 + hv.y * wg1 + hv.z * wg2 + hv.w * wg3;
                    }
                }
#pragma unroll
                for (int bl = 0; bl < 4; ++bl)
                    redA[(jj * 4 + bl) * 36 + kp] = ag[bl];
            }
            __syncthreads();
            if (tid < 32) {
                float4 s4 = {0, 0, 0, 0};
#pragma unroll
                for (int c = 0; c < 8; ++c) {
                    float4 v = *(const float4*)&redA[tid * 36 + c * 4];
                    s4.x += v.x; s4.y += v.y; s4.z += v.z; s4.w += v.w;
                }
                float sg = (s4.x + s4.y) + (s4.z + s4.w);
                float g = sigmoidf_(sg + gav);
                float hn = g * hpv + (1.0f - g) * av;
                __hip_atomic_store(hbuf + (size_t)fbg * D + fd, hn,
                                   __ATOMIC_RELAXED, __HIP_MEMORY_SCOPE_AGENT);
                if (s == NSTEPS - 1) out[((size_t)fbg * T + t) * D + fd] = hn;
            }
            asm volatile("s_waitcnt vmcnt(0)" ::: "memory");
            __syncthreads();
            ++bar;
            if (tid == 0)
                __hip_atomic_store(flagbase + pos * FLAG_STRIDE, bar,
                                   __ATOMIC_RELAXED, __HIP_MEMORY_SCOPE_AGENT);
        }
    }
#undef POLL_AND_STAGE
}

// ---------------------------------------------------------------------------
extern "C" void kernel_launch(void* const* d_in, const int* in_sizes, int n_in,
                              void* d_out, int out_size, void* d_ws, size_t ws_size,
                              hipStream_t stream)
{
    const float* x          = (const float*)d_in[0];
    const float* in_proj_w  = (const float*)d_in[1];
    const float* in_proj_b  = (const float*)d_in[2];
    const float* out_proj_w = (const float*)d_in[3];
    const float* out_proj_b = (const float*)d_in[4];
    const float* w_ih       = (const float*)d_in[5];
    const float* w_hh       = (const float*)d_in[6];
    const float* b_ih       = (const float*)d_in[7];
    const float* b_hh       = (const float*)d_in[8];
    const float* gate_w     = (const float*)d_in[9];
    const float* gate_b     = (const float*)d_in[10];
    float* out = (float*)d_out;

    float* ws = (float*)d_ws;
    const size_t S1 = (size_t)B * H * T * DH;   // 8,388,608 floats
    float* qb   = ws;
    float* kb   = ws + S1;
    float* vb   = ws + 2 * S1;
    float* ctx  = ws + 3 * S1;
    float* attn = ws + 4 * S1;
    float* ga   = ws + 5 * S1;
    float* gi   = ws;                           // overlaps q/k/v
    float* hbuf  = ws + 6 * S1;
    float* hpbuf = hbuf + B * D;
    unsigned* flags = (unsigned*)(hpbuf + B * D);  // 2 chains *128 flags *64B

    dim3 blk(256);

    gemm_kernel<1><<<dim3(128, 48), blk, 0, stream>>>(
        x, in_proj_w, in_proj_b, nullptr, B * T, 3 * D, D, D, 0, qb, kb, vb);
    attn_kernel<<<dim3(2048), blk, 0, stream>>>(qb, kb, vb, ctx);
    gemm_kernel<0><<<dim3(128, 16), blk, 0, stream>>>(
        ctx, out_proj_w, out_proj_b, attn, B * T, D, D, D, 0,
        nullptr, nullptr, nullptr);
    gemm_kernel<0><<<dim3(128, 16), blk, 0, stream>>>(
        attn, gate_w, gate_b, ga, B * T, D, D, 2 * D, D,
        nullptr, nullptr, nullptr);
    gemm_kernel<0><<<dim3(128, 48), blk, 0, stream>>>(
        x, w_ih, b_ih, gi, B * T, 3 * D, D, D, 0,
        nullptr, nullptr, nullptr);

    // zero h, hp, and flags every launch (graph-replay deterministic)
    hipMemsetAsync(hbuf, 0,
                   (2 * (size_t)B * D) * sizeof(float) +
                   NCHAIN * NBLK_CHAIN * FLAG_STRIDE * sizeof(unsigned),
                   stream);

    // needs (4096 + 96*36 + 96)*4 ~= 30 KB; request 96 KB to force 1 block/CU
    const int LDS_BYTES = 98304;
    static bool attr_done = false;
    if (!attr_done) {
        hipFuncSetAttribute((const void*)gru_persistent,
                            hipFuncAttributeMaxDynamicSharedMemorySize, LDS_BYTES);
        attr_done = true;
    }
    gru_persistent<<<dim3(NCHAIN * NBLK_CHAIN), blk, LDS_BYTES, stream>>>(
        w_hh, b_hh, gate_w, gi, ga, attn, out, hbuf, hpbuf, flags);
}

// Round 8
// 35448.236 us; speedup vs baseline: 1.9704x; 1.0012x over previous
//
#include <hip/hip_runtime.h>
#include <hip/hip_bf16.h>
#include <math.h>
#include <stdint.h>

#define B 8
#define T 1024
#define D 1024
#define H 16
#define DH 64
#define NSTEPS 4

#define NCHAIN 2            // batch split into 2 independent chains of 4 rows
#define NBLK_CHAIN 128      // blocks per chain
#define DIMS_PER_BLK 8      // 128 * 8 = 1024 dims

#define FLAG_STRIDE 16      // flags 64B apart (own cache line each)
#define RED_PITCH 37        // redA pitch (coprime to 32 -> conflict-free cols)

__device__ __forceinline__ float sigmoidf_(float x) { return 1.0f / (1.0f + expf(-x)); }

// bf16 round-to-nearest-even, returned in low 16 bits
__device__ __forceinline__ unsigned bf16rne(float f) {
    unsigned x = __float_as_uint(f);
    return (x + 0x7FFFu + ((x >> 16) & 1u)) >> 16;
}
// unpack u32 = bf0 | bf1<<16 into two f32
#define UNPK(u, f0, f1)                                                       \
    { f0 = __uint_as_float((u) << 16); f1 = __uint_as_float((u) & 0xFFFF0000u); }

// ---------------------------------------------------------------------------
// Generic tiled fp32 GEMM: C[M,N] = A[M,K] @ W[N,K]^T + bias[N]
// MODE 0: C[m*N + n];  MODE 1: qkv scatter to q/k/v [B*H, T, DH]
// ---------------------------------------------------------------------------
template <int MODE>
__global__ __launch_bounds__(256) void gemm_kernel(
    const float* __restrict__ A, const float* __restrict__ W,
    const float* __restrict__ bias, float* __restrict__ C,
    int M, int N, int K, int ldw, int koff,
    float* __restrict__ qb, float* __restrict__ kb, float* __restrict__ vb)
{
    __shared__ float As[32][68];
    __shared__ float Ws[32][68];
    const int m0 = blockIdx.x * 64, n0 = blockIdx.y * 64;
    const int tid = threadIdx.x;
    const int tn = tid & 15, tm = tid >> 4;
    float acc[4][4] = {};

    for (int k0 = 0; k0 < K; k0 += 32) {
#pragma unroll
        for (int j = 0; j < 2; ++j) {
            int lin = tid + j * 256;
            int r = lin >> 3, c4 = lin & 7;
            float4 av = *(const float4*)(A + (size_t)(m0 + r) * K + k0 + c4 * 4);
            As[c4 * 4 + 0][r] = av.x; As[c4 * 4 + 1][r] = av.y;
            As[c4 * 4 + 2][r] = av.z; As[c4 * 4 + 3][r] = av.w;
            float4 wv = *(const float4*)(W + (size_t)(n0 + r) * ldw + koff + k0 + c4 * 4);
            Ws[c4 * 4 + 0][r] = wv.x; Ws[c4 * 4 + 1][r] = wv.y;
            Ws[c4 * 4 + 2][r] = wv.z; Ws[c4 * 4 + 3][r] = wv.w;
        }
        __syncthreads();
#pragma unroll
        for (int k = 0; k < 32; ++k) {
            float a_[4], b_[4];
            *(float4*)a_ = *(const float4*)&As[k][tm * 4];
            *(float4*)b_ = *(const float4*)&Ws[k][tn * 4];
#pragma unroll
            for (int i = 0; i < 4; ++i)
#pragma unroll
                for (int j = 0; j < 4; ++j) acc[i][j] += a_[i] * b_[j];
        }
        __syncthreads();
    }

#pragma unroll
    for (int i = 0; i < 4; ++i) {
        int m = m0 + tm * 4 + i;
#pragma unroll
        for (int j = 0; j < 4; ++j) {
            int n = n0 + tn * 4 + j;
            float v = acc[i][j] + bias[n];
            if (MODE == 0) {
                C[(size_t)m * N + n] = v;
            } else {
                int which = n >> 10;
                int hh = (n & 1023) >> 6;
                int dh = n & 63;
                int b = m >> 10, t = m & 1023;
                float* dst = (which == 0) ? qb : ((which == 1) ? kb : vb);
                dst[(((size_t)(b * H + hh)) * T + t) * DH + dh] = v;
            }
        }
    }
}

// ---------------------------------------------------------------------------
// Flash attention fp32 (unchanged)
// ---------------------------------------------------------------------------
__global__ __launch_bounds__(256) void attn_kernel(
    const float* __restrict__ qb, const float* __restrict__ kb,
    const float* __restrict__ vb, float* __restrict__ ctx)
{
    __shared__ float Qs[64][65];
    __shared__ float Ks[64][65];
    __shared__ float Vs[64][65];
    __shared__ float mrow[64], lrow[64], srow[64];
    __shared__ float tred[64][4];

    const int tid = threadIdx.x;
    const int row = tid & 63, seg = tid >> 6;
    const int bx = blockIdx.x;
    const int qblk = bx & 15;
    const int bh = bx >> 4;
    const float* qp = qb + (size_t)bh * T * DH;
    const float* kp = kb + (size_t)bh * T * DH;
    const float* vp = vb + (size_t)bh * T * DH;

#pragma unroll
    for (int i = 0; i < 4; ++i) {
        int lin = tid + i * 256;
        int r = lin >> 4, c4 = lin & 15;
        float4 v = *(const float4*)(qp + (size_t)(qblk * 64 + r) * DH + c4 * 4);
        Qs[r][c4 * 4 + 0] = v.x; Qs[r][c4 * 4 + 1] = v.y;
        Qs[r][c4 * 4 + 2] = v.z; Qs[r][c4 * 4 + 3] = v.w;
    }
    if (tid < 64) { mrow[tid] = -3.0e38f; lrow[tid] = 0.0f; }

    float Oacc[16];
#pragma unroll
    for (int j = 0; j < 16; ++j) Oacc[j] = 0.0f;

    for (int kt = 0; kt < 16; ++kt) {
        __syncthreads();
#pragma unroll
        for (int i = 0; i < 4; ++i) {
            int lin = tid + i * 256;
            int r = lin >> 4, c4 = lin & 15;
            float4 kv = *(const float4*)(kp + (size_t)(kt * 64 + r) * DH + c4 * 4);
            Ks[r][c4 * 4 + 0] = kv.x; Ks[r][c4 * 4 + 1] = kv.y;
            Ks[r][c4 * 4 + 2] = kv.z; Ks[r][c4 * 4 + 3] = kv.w;
            float4 vv = *(const float4*)(vp + (size_t)(kt * 64 + r) * DH + c4 * 4);
            Vs[r][c4 * 4 + 0] = vv.x; Vs[r][c4 * 4 + 1] = vv.y;
            Vs[r][c4 * 4 + 2] = vv.z; Vs[r][c4 * 4 + 3] = vv.w;
        }
        __syncthreads();

        float sacc[16];
#pragma unroll
        for (int j = 0; j < 16; ++j) sacc[j] = 0.0f;
        for (int k = 0; k < 64; ++k) {
            float qv = Qs[row][k];
#pragma unroll
            for (int j = 0; j < 16; ++j) sacc[j] += qv * Ks[seg * 16 + j][k];
        }
        float tmax = -3.0e38f;
#pragma unroll
        for (int j = 0; j < 16; ++j) { sacc[j] *= 0.125f; tmax = fmaxf(tmax, sacc[j]); }
        tred[row][seg] = tmax;
        __syncthreads();
        if (seg == 0) {
            float mt = fmaxf(fmaxf(tred[row][0], tred[row][1]),
                             fmaxf(tred[row][2], tred[row][3]));
            float mo = mrow[row];
            float mn = fmaxf(mo, mt);
            srow[row] = expf(mo - mn);
            mrow[row] = mn;
        }
        __syncthreads();
        float mn = mrow[row], sc = srow[row];
        float psum = 0.0f;
#pragma unroll
        for (int j = 0; j < 16; ++j) {
            float p = expf(sacc[j] - mn);
            Ks[row][seg * 16 + j] = p;
            psum += p;
        }
        tred[row][seg] = psum;
#pragma unroll
        for (int j = 0; j < 16; ++j) Oacc[j] *= sc;
        __syncthreads();
        if (seg == 0)
            lrow[row] = lrow[row] * sc +
                        (tred[row][0] + tred[row][1] + tred[row][2] + tred[row][3]);
        for (int kj = 0; kj < 64; ++kj) {
            float pv = Ks[row][kj];
#pragma unroll
            for (int j = 0; j < 16; ++j) Oacc[j] += pv * Vs[kj][seg * 16 + j];
        }
    }
    __syncthreads();
    float linv = 1.0f / lrow[row];
    int b = bh >> 4, hh = bh & 15;
    int q = qblk * 64 + row;
#pragma unroll
    for (int j = 0; j < 16; ++j)
        ctx[((size_t)(b * T + q)) * D + hh * 64 + seg * 16 + j] = Oacc[j] * linv;
}

// ---------------------------------------------------------------------------
// Persistent GRU recurrence, R7 protocol with 3 handshake cuts:
//  (1) early flag: only wave 0 produces cross-block data, so only wave 0
//      drains vmcnt and lane 0 stores the flag -- no block barrier first;
//      waves 1-3 proceed straight to the next poll.
//  (2) rowreduce+finalize merged: tid<32 reduce their redA rows directly
//      (pitch-37 scratch, conflict-free b128 columns) -- 2 barriers/phase.
//  (3) u64 staging: 8 atomic u64 loads per thread from exactly 2 source
//      blocks; poll srcA -> load -> poll srcB -> load (overlaps arrival).
// Hazard notes: ho is read from sh BEFORE bar2 (next-phase staging may
// overwrite sh while wave 0 finalizes); redA reads (pre-bar1-of-next-phase)
// vs next dot's redA writes (post-bar1) are barrier-separated.
// ---------------------------------------------------------------------------
__global__ __launch_bounds__(256, 1) void gru_persistent(
    const float* __restrict__ w_hh, const float* __restrict__ b_hh,
    const float* __restrict__ gate_w,
    const float* __restrict__ gi, const float* __restrict__ ga,
    const float* __restrict__ attn, float* __restrict__ out,
    float* __restrict__ hbuf, float* __restrict__ hpbuf,
    unsigned* __restrict__ flags)
{
    extern __shared__ float lds[];
    float* sh   = lds;                     // [4][1024] staged h or hp
    float* redA = lds + 4096;              // [96][37] partial scratch

    const int tid = threadIdx.x;
    const int chain = blockIdx.x & 1;
    const int pos = blockIdx.x >> 1;            // 0..127
    const int d0 = pos * DIMS_PER_BLK;
    const int kp = tid & 31, jj = tid >> 5;
    const int d = d0 + jj;

    // ---- resident weights in VGPRs (packed bf16), k = c*128 + kp*4 + {0..3}
    unsigned wpk[4][16];
#pragma unroll
    for (int tt = 0; tt < 4; ++tt) {
        const float* src = (tt < 3) ? (w_hh + ((size_t)(tt * D) + d) * D)
                                    : (gate_w + (size_t)d * (2 * D));
#pragma unroll
        for (int c = 0; c < 8; ++c) {
            float4 v = *(const float4*)(src + c * 128 + kp * 4);
            wpk[tt][c * 2]     = bf16rne(v.x) | (bf16rne(v.y) << 16);
            wpk[tt][c * 2 + 1] = bf16rne(v.z) | (bf16rne(v.w) << 16);
        }
    }

    // finalize-thread constants (tid < 32: jj2 = tid>>2, bl = tid&3)
    float bfr = 0.0f, bfz = 0.0f, bfn = 0.0f;
    int fd = 0, fbg = 0;
    if (tid < 32) {
        int jj2 = tid >> 2, bl = tid & 3;
        fd = d0 + jj2;
        fbg = chain * 4 + bl;
        bfr = b_hh[fd]; bfz = b_hh[D + fd]; bfn = b_hh[2 * D + fd];
    }

    unsigned* flagbase = flags + (size_t)chain * NBLK_CHAIN * FLAG_STRIDE;
    const int srcA = (2 * tid) >> 3;            // 0..63
    const int srcB = srcA + 64;                 // 64..127
    const float* hsrc  = hbuf  + (size_t)chain * 4 * D;
    const float* hpsrc = hpbuf + (size_t)chain * 4 * D;

    unsigned bar = 0;                           // completed-phase epoch
    float hpv = 0.0f;                           // finalize threads only

#define POLL_AND_STAGE(SRC)                                                   \
    {                                                                         \
        const unsigned long long* p64_ = (const unsigned long long*)(SRC);    \
        while (__hip_atomic_load(flagbase + srcA * FLAG_STRIDE,               \
                   __ATOMIC_RELAXED, __HIP_MEMORY_SCOPE_AGENT) < bar) {}      \
        unsigned long long ra_[4];                                            \
        _Pragma("unroll")                                                     \
        for (int i = 0; i < 4; ++i)                                           \
            ra_[i] = __hip_atomic_load(p64_ + i * 512 + tid,                  \
                         __ATOMIC_RELAXED, __HIP_MEMORY_SCOPE_AGENT);         \
        while (__hip_atomic_load(flagbase + srcB * FLAG_STRIDE,               \
                   __ATOMIC_RELAXED, __HIP_MEMORY_SCOPE_AGENT) < bar) {}      \
        unsigned long long rb_[4];                                            \
        _Pragma("unroll")                                                     \
        for (int i = 0; i < 4; ++i)                                           \
            rb_[i] = __hip_atomic_load(p64_ + i * 512 + 256 + tid,            \
                         __ATOMIC_RELAXED, __HIP_MEMORY_SCOPE_AGENT);         \
        unsigned long long* sh64_ = (unsigned long long*)sh;                  \
        _Pragma("unroll")                                                     \
        for (int i = 0; i < 4; ++i) {                                         \
            sh64_[i * 512 + tid]       = ra_[i];                              \
            sh64_[i * 512 + 256 + tid] = rb_[i];                              \
        }                                                                     \
    }                                                                         \
    __syncthreads();

    for (int t = 0; t < T; ++t) {
        // per-t inputs for the finalize threads (wave 0 lanes; latency hides
        // under poll/stage/dot)
        float giR = 0, giZ = 0, giN = 0, gav = 0, av = 0;
        if (tid < 32) {
            const size_t base = (size_t)fbg * T + t;
            const float* gib = gi + base * (3 * D);
            giR = gib[fd]; giZ = gib[D + fd]; giN = gib[2 * D + fd];
            gav = ga[base * D + fd];
            av  = attn[base * D + fd];
        }
        for (int s = 0; s < NSTEPS; ++s) {
            // ================= phase A: gh = h @ w_hh^T =================
            POLL_AND_STAGE(hsrc)
            float ho = 0.0f;
            if (tid < 32) ho = sh[(tid & 3) * 1024 + fd];   // pre-bar2 read
            {
                float ar[4] = {0, 0, 0, 0}, az[4] = {0, 0, 0, 0}, an[4] = {0, 0, 0, 0};
#pragma unroll
                for (int c = 0; c < 8; ++c) {
                    float wr0, wr1, wr2, wr3, wz0, wz1, wz2, wz3;
                    float wn0, wn1, wn2, wn3;
                    UNPK(wpk[0][c * 2],     wr0, wr1)
                    UNPK(wpk[0][c * 2 + 1], wr2, wr3)
                    UNPK(wpk[1][c * 2],     wz0, wz1)
                    UNPK(wpk[1][c * 2 + 1], wz2, wz3)
                    UNPK(wpk[2][c * 2],     wn0, wn1)
                    UNPK(wpk[2][c * 2 + 1], wn2, wn3)
                    const int ha = c * 128 + kp * 4;
#pragma unroll
                    for (int bl = 0; bl < 4; ++bl) {
                        float4 hv = *(const float4*)&sh[bl * 1024 + ha];
                        ar[bl] += hv.x * wr0 + hv.y * wr1 + hv.z * wr2 + hv.w * wr3;
                        az[bl] += hv.x * wz0 + hv.y * wz1 + hv.z * wz2 + hv.w * wz3;
                        an[bl] += hv.x * wn0 + hv.y * wn1 + hv.z * wn2 + hv.w * wn3;
                    }
                }
#pragma unroll
                for (int bl = 0; bl < 4; ++bl) {
                    redA[(jj * 12 + 0 + bl) * RED_PITCH + kp] = ar[bl];
                    redA[(jj * 12 + 4 + bl) * RED_PITCH + kp] = az[bl];
                    redA[(jj * 12 + 8 + bl) * RED_PITCH + kp] = an[bl];
                }
            }
            __syncthreads();                    // bar2: redA ready, sh free
            if (tid < 32) {
                int base = (tid >> 2) * 12 + (tid & 3);
                float sr = 0, sz = 0, sn = 0;
#pragma unroll
                for (int c = 0; c < 8; ++c) {
                    float4 r4 = *(const float4*)&redA[(base    ) * RED_PITCH + c * 4];
                    float4 z4 = *(const float4*)&redA[(base + 4) * RED_PITCH + c * 4];
                    float4 n4 = *(const float4*)&redA[(base + 8) * RED_PITCH + c * 4];
                    sr += (r4.x + r4.y) + (r4.z + r4.w);
                    sz += (z4.x + z4.y) + (z4.z + z4.w);
                    sn += (n4.x + n4.y) + (n4.z + n4.w);
                }
                float r_ = sigmoidf_(giR + sr + bfr);
                float z_ = sigmoidf_(giZ + sz + bfz);
                float n_ = tanhf(giN + r_ * (sn + bfn));
                hpv = (1.0f - z_) * n_ + z_ * ho;
                __hip_atomic_store(hpbuf + (size_t)fbg * D + fd, hpv,
                                   __ATOMIC_RELAXED, __HIP_MEMORY_SCOPE_AGENT);
            }
            ++bar;
            if (tid < 64) {                     // wave 0 only: drain + flag
                asm volatile("s_waitcnt vmcnt(0)" ::: "memory");
                if (tid == 0)
                    __hip_atomic_store(flagbase + pos * FLAG_STRIDE, bar,
                                       __ATOMIC_RELAXED, __HIP_MEMORY_SCOPE_AGENT);
            }

            // ============ phase B: g = sigmoid(hp @ gwL^T + ga) ==========
            POLL_AND_STAGE(hpsrc)
            {
                float ag[4] = {0, 0, 0, 0};
#pragma unroll
                for (int c = 0; c < 8; ++c) {
                    float wg0, wg1, wg2, wg3;
                    UNPK(wpk[3][c * 2],     wg0, wg1)
                    UNPK(wpk[3][c * 2 + 1], wg2, wg3)
                    const int ha = c * 128 + kp * 4;
#pragma unroll
                    for (int bl = 0; bl < 4; ++bl) {
                        float4 hv = *(const float4*)&sh[bl * 1024 + ha];
                        ag[bl] += hv.x * wg0 + hv.y * wg1 + hv.z * wg2 + hv.w * wg3;
                    }
                }
#pragma unroll
                for (int bl = 0; bl < 4; ++bl)
                    redA[(jj * 4 + bl) * RED_PITCH + kp] = ag[bl];
            }
            __syncthreads();                    // bar2
            if (tid < 32) {
                float sg = 0;
#pragma unroll
                for (int c = 0; c < 8; ++c) {
                    float4 v = *(const float4*)&redA[tid * RED_PITCH + c * 4];
                    sg += (v.x + v.y) + (v.z + v.w);
                }
                float g = sigmoidf_(sg + gav);
                float hn = g * hpv + (1.0f - g) * av;
                __hip_atomic_store(hbuf + (size_t)fbg * D + fd, hn,
                                   __ATOMIC_RELAXED, __HIP_MEMORY_SCOPE_AGENT);
                if (s == NSTEPS - 1) out[((size_t)fbg * T + t) * D + fd] = hn;
            }
            ++bar;
            if (tid < 64) {                     // wave 0 only: drain + flag
                asm volatile("s_waitcnt vmcnt(0)" ::: "memory");
                if (tid == 0)
                    __hip_atomic_store(flagbase + pos * FLAG_STRIDE, bar,
                                       __ATOMIC_RELAXED, __HIP_MEMORY_SCOPE_AGENT);
            }
        }
    }
#undef POLL_AND_STAGE
}

// ---------------------------------------------------------------------------
extern "C" void kernel_launch(void* const* d_in, const int* in_sizes, int n_in,
                              void* d_out, int out_size, void* d_ws, size_t ws_size,
                              hipStream_t stream)
{
    const float* x          = (const float*)d_in[0];
    const float* in_proj_w  = (const float*)d_in[1];
    const float* in_proj_b  = (const float*)d_in[2];
    const float* out_proj_w = (const float*)d_in[3];
    const float* out_proj_b = (const float*)d_in[4];
    const float* w_ih       = (const float*)d_in[5];
    const float* w_hh       = (const float*)d_in[6];
    const float* b_ih       = (const float*)d_in[7];
    const float* b_hh       = (const float*)d_in[8];
    const float* gate_w     = (const float*)d_in[9];
    const float* gate_b     = (const float*)d_in[10];
    float* out = (float*)d_out;

    float* ws = (float*)d_ws;
    const size_t S1 = (size_t)B * H * T * DH;   // 8,388,608 floats
    float* qb   = ws;
    float* kb   = ws + S1;
    float* vb   = ws + 2 * S1;
    float* ctx  = ws + 3 * S1;
    float* attn = ws + 4 * S1;
    float* ga   = ws + 5 * S1;
    float* gi   = ws;                           // overlaps q/k/v
    float* hbuf  = ws + 6 * S1;
    float* hpbuf = hbuf + B * D;
    unsigned* flags = (unsigned*)(hpbuf + B * D);  // 2 chains *128 flags *64B

    dim3 blk(256);

    gemm_kernel<1><<<dim3(128, 48), blk, 0, stream>>>(
        x, in_proj_w, in_proj_b, nullptr, B * T, 3 * D, D, D, 0, qb, kb, vb);
    attn_kernel<<<dim3(2048), blk, 0, stream>>>(qb, kb, vb, ctx);
    gemm_kernel<0><<<dim3(128, 16), blk, 0, stream>>>(
        ctx, out_proj_w, out_proj_b, attn, B * T, D, D, D, 0,
        nullptr, nullptr, nullptr);
    gemm_kernel<0><<<dim3(128, 16), blk, 0, stream>>>(
        attn, gate_w, gate_b, ga, B * T, D, D, 2 * D, D,
        nullptr, nullptr, nullptr);
    gemm_kernel<0><<<dim3(128, 48), blk, 0, stream>>>(
        x, w_ih, b_ih, gi, B * T, 3 * D, D, D, 0,
        nullptr, nullptr, nullptr);

    // zero h, hp, and flags every launch (graph-replay deterministic)
    hipMemsetAsync(hbuf, 0,
                   (2 * (size_t)B * D) * sizeof(float) +
                   NCHAIN * NBLK_CHAIN * FLAG_STRIDE * sizeof(unsigned),
                   stream);

    // needs (4096 + 96*37)*4 ~= 30.6 KB; request 96 KB to force 1 block/CU
    const int LDS_BYTES = 98304;
    static bool attr_done = false;
    if (!attr_done) {
        hipFuncSetAttribute((const void*)gru_persistent,
                            hipFuncAttributeMaxDynamicSharedMemorySize, LDS_BYTES);
        attr_done = true;
    }
    gru_persistent<<<dim3(NCHAIN * NBLK_CHAIN), blk, LDS_BYTES, stream>>>(
        w_hh, b_hh, gate_w, gi, ga, attn, out, hbuf, hpbuf, flags);
}